// Round 2
// baseline (585.293 us; speedup 1.0000x reference)
//
#include <hip/hip_runtime.h>

// B-spline basis, DF=16, DEGREE=3, fixed knots:
// KNOTS = [0,0,0] ++ linspace(0, 1+1e-7, 14) ++ [1,1,1]   (20 knots)
// Output shape (32, 131072, 16) float32.
// Memory-bound: 268 MB out + 17 MB in => ~46 us floor at 6.3 TB/s.
//
// R1 lesson: per-thread 16-float row stores (64B lane stride) issue 64 partial
// 16B sector writes per instruction -> ~920 GB/s. Fix: 4x4 float4 transpose
// across lane quads via shfl_xor so every store writes full 64B sectors.

namespace {

struct Tables {
    float knot[20];
    float r1[3][18];   // 1/(knot[p+i]   - knot[i]   + 1e-15), p=1..3
    float r2[3][18];   // 1/(knot[p+1+i] - knot[1+i] + 1e-15)
};

constexpr Tables make_tables() {
    Tables T{};
    const double step = (1.0 + 1e-07) / 13.0;
    for (int i = 0; i < 20; ++i) {
        double v;
        if (i < 3)        v = 0.0;
        else if (i <= 15) v = step * (i - 3);     // linspace pts 0..12
        else if (i == 16) v = 1.0 + 1e-07;        // linspace endpoint exact
        else              v = 1.0;
        T.knot[i] = (float)v;
    }
    for (int p = 1; p <= 3; ++p) {
        for (int i = 0; i < 19 - p; ++i) {
            T.r1[p - 1][i] = 1.0f / (T.knot[p + i]     - T.knot[i]     + 1e-15f);
            T.r2[p - 1][i] = 1.0f / (T.knot[p + 1 + i] - T.knot[1 + i] + 1e-15f);
        }
    }
    return T;
}

__device__ inline float4 shfl_xor_f4(float4 v, int mask) {
    float4 r;
    r.x = __shfl_xor(v.x, mask);
    r.y = __shfl_xor(v.y, mask);
    r.z = __shfl_xor(v.z, mask);
    r.w = __shfl_xor(v.w, mask);
    return r;
}

} // namespace

__global__ __launch_bounds__(256) void bspline_basis_kernel(
    const float* __restrict__ ts, float* __restrict__ out, int n)
{
    constexpr Tables T = make_tables();

    int gid = blockIdx.x * blockDim.x + threadIdx.x;
    // n is a multiple of 256 (32*131072); grid covers it exactly. Clamp just
    // in case so shuffles always see live lanes.
    int e = gid < n ? gid : (n - 1);

    float t = ts[e];

    // Degree 0: indicator of knot interval (zero-width intervals fold away at
    // compile time since knot[] is constexpr).
    float B[19];
#pragma unroll
    for (int i = 0; i < 19; ++i) {
        float kL = T.knot[i], kR = T.knot[i + 1];
        B[i] = (kR > kL && t >= kL && t < kR) ? 1.0f : 0.0f;
    }

    // Cox-de Boor recursion, denominators pre-reciprocated at compile time.
#pragma unroll
    for (int p = 1; p <= 3; ++p) {
#pragma unroll
        for (int i = 0; i < 19 - p; ++i) {
            float a = (t - T.knot[i]) * T.r1[p - 1][i];
            float b = (T.knot[p + 1 + i] - t) * T.r2[p - 1][i];
            B[i] = a * B[i] + b * B[i + 1];
        }
    }

    // Lane quad transpose: lane l of the quad currently holds the full row of
    // element quad_base+l as 4 float4 quarters x[0..3]. After two butterfly
    // stages, v[k] = quarter l of element quad_base+k, so each store
    // instruction writes full 64B-aligned sectors.
    float4 x[4];
    x[0] = make_float4(B[0],  B[1],  B[2],  B[3]);
    x[1] = make_float4(B[4],  B[5],  B[6],  B[7]);
    x[2] = make_float4(B[8],  B[9],  B[10], B[11]);
    x[3] = make_float4(B[12], B[13], B[14], B[15]);

    int l = threadIdx.x & 3;

    float4 w[4];
#pragma unroll
    for (int k = 0; k < 4; ++k) {
        float4 sh = shfl_xor_f4(x[k ^ 1], 1);
        w[k] = ((k ^ l) & 1) ? sh : x[k];
    }
    float4 v[4];
#pragma unroll
    for (int k = 0; k < 4; ++k) {
        float4 sh = shfl_xor_f4(w[k ^ 2], 2);
        v[k] = ((k ^ l) & 2) ? sh : w[k];
    }

    // Element quad this thread's quad covers: elements 4q..4q+3.
    size_t q = (size_t)(gid >> 2);
    float4* o = reinterpret_cast<float4*>(out);
#pragma unroll
    for (int k = 0; k < 4; ++k) {
        size_t elem = q * 4 + k;
        if (elem < (size_t)n) {
            o[elem * 4 + l] = v[k];
        }
    }
}

extern "C" void kernel_launch(void* const* d_in, const int* in_sizes, int n_in,
                              void* d_out, int out_size, void* d_ws, size_t ws_size,
                              hipStream_t stream) {
    const float* ts = (const float*)d_in[0];
    float* out = (float*)d_out;
    int n = in_sizes[0];  // 32 * 131072 = 4194304

    const int block = 256;
    const int grid = (n + block - 1) / block;
    bspline_basis_kernel<<<grid, block, 0, stream>>>(ts, out, n);
}

// Round 3
// 272.292 us; speedup vs baseline: 2.1495x; 2.1495x over previous
//
#include <hip/hip_runtime.h>

// B-spline basis, DF=16, DEGREE=3, fixed knots:
// KNOTS = [0,0,0] ++ linspace(0, 1+1e-7, 14) ++ [1,1,1]   (20 knots)
// Output shape (32, 131072, 16) float32.
// Memory-bound: 268 MB out + 17 MB in => ~46 us floor at 6.3 TB/s.
//
// R1 lesson: per-thread 16-float row stores -> 64 partial 16B sector writes
//   per instr -> ~1 TB/s effective.
// R2 lesson: quad-shuffle transpose gave full 64B chunks but a 256B-strided
//   wave footprint -> L2 RMW: FETCH_SIZE 20x ideal, WRITE_SIZE 4.5x ideal.
// R3 fix: LDS transpose; drain in output-linear order so every store instr
//   covers one contiguous aligned 1 KB span per wave (fillBuffer pattern,
//   which measures 6.3 TB/s on this same buffer).

namespace {

struct Tables {
    float knot[20];
    float r1[3][18];   // 1/(knot[p+i]   - knot[i]   + 1e-15), p=1..3
    float r2[3][18];   // 1/(knot[p+1+i] - knot[1+i] + 1e-15)
};

constexpr Tables make_tables() {
    Tables T{};
    const double step = (1.0 + 1e-07) / 13.0;
    for (int i = 0; i < 20; ++i) {
        double v;
        if (i < 3)        v = 0.0;
        else if (i <= 15) v = step * (i - 3);     // linspace pts 0..12
        else if (i == 16) v = 1.0 + 1e-07;        // linspace endpoint exact
        else              v = 1.0;
        T.knot[i] = (float)v;
    }
    for (int p = 1; p <= 3; ++p) {
        for (int i = 0; i < 19 - p; ++i) {
            T.r1[p - 1][i] = 1.0f / (T.knot[p + i]     - T.knot[i]     + 1e-15f);
            T.r2[p - 1][i] = 1.0f / (T.knot[p + 1 + i] - T.knot[1 + i] + 1e-15f);
        }
    }
    return T;
}

} // namespace

// Row stride 5 float4 (4 data + 1 pad) = 20 banks: both LDS phases hit all
// 8 bank-quads uniformly (only the inherent b128 aliasing). 20 KB/block ->
// 8 blocks/CU, full occupancy.
#define ROW_STRIDE 5

__global__ __launch_bounds__(256) void bspline_basis_kernel(
    const float* __restrict__ ts, float* __restrict__ out, int n)
{
    constexpr Tables T = make_tables();

    __shared__ float4 lds[256 * ROW_STRIDE];

    const int tid = threadIdx.x;
    const int gid = blockIdx.x * 256 + tid;

    // ---- Phase 1: one element per thread, full recursion in registers ----
    {
        int e = gid < n ? gid : (n - 1);
        float t = ts[e];

        float B[19];
#pragma unroll
        for (int i = 0; i < 19; ++i) {
            float kL = T.knot[i], kR = T.knot[i + 1];
            B[i] = (kR > kL && t >= kL && t < kR) ? 1.0f : 0.0f;
        }

#pragma unroll
        for (int p = 1; p <= 3; ++p) {
#pragma unroll
            for (int i = 0; i < 19 - p; ++i) {
                float a = (t - T.knot[i]) * T.r1[p - 1][i];
                float b = (T.knot[p + 1 + i] - t) * T.r2[p - 1][i];
                B[i] = a * B[i] + b * B[i + 1];
            }
        }

        float4* row = &lds[tid * ROW_STRIDE];
        row[0] = make_float4(B[0],  B[1],  B[2],  B[3]);
        row[1] = make_float4(B[4],  B[5],  B[6],  B[7]);
        row[2] = make_float4(B[8],  B[9],  B[10], B[11]);
        row[3] = make_float4(B[12], B[13], B[14], B[15]);
    }

    __syncthreads();

    // ---- Phase 2: drain LDS in output-linear order ----
    // Block covers float4 indices [blockIdx.x*1024, +1024) of out.
    // Thread j stores indices j + 256m: each store instr = one contiguous,
    // aligned 1 KB wave span.
    float4* o = reinterpret_cast<float4*>(out) + (size_t)blockIdx.x * 1024;
    const size_t limit = (size_t)n * 4;  // total float4 count
    const size_t base4 = (size_t)blockIdx.x * 1024;
#pragma unroll
    for (int m = 0; m < 4; ++m) {
        int idx = tid + 256 * m;          // block-local float4 index
        int e = idx >> 2;                 // source element (row in LDS)
        int l = idx & 3;                  // which quarter of the row
        float4 v = lds[e * ROW_STRIDE + l];
        if (base4 + (size_t)idx < limit) {
            o[idx] = v;
        }
    }
}

extern "C" void kernel_launch(void* const* d_in, const int* in_sizes, int n_in,
                              void* d_out, int out_size, void* d_ws, size_t ws_size,
                              hipStream_t stream) {
    const float* ts = (const float*)d_in[0];
    float* out = (float*)d_out;
    int n = in_sizes[0];  // 32 * 131072 = 4194304

    const int block = 256;
    const int grid = (n + block - 1) / block;
    bspline_basis_kernel<<<grid, block, 0, stream>>>(ts, out, n);
}

// Round 5
// 267.639 us; speedup vs baseline: 2.1869x; 1.0174x over previous
//
#include <hip/hip_runtime.h>

// B-spline basis, DF=16, DEGREE=3, fixed knots:
// KNOTS = [0,0,0] ++ linspace(0, 1+1e-7, 14) ++ [1,1,1]   (20 knots)
// Output shape (32, 131072, 16) float32.
// Memory-bound: 268 MB out + 17 MB in => ~46 us floor at 6.3 TB/s.
//
// R1: per-thread row stores -> 64 partial sector writes/instr -> ~3 TB/s.
// R2: quad-shuffle transpose -> 256B-strided wave footprint -> L2 RMW,
//     FETCH 20x ideal, WRITE 4.5x ideal. Worst round.
// R3: LDS transpose + output-linear drain (1KB contiguous per wave-instr,
//     fillBuffer pattern) -> kernel ~57us, ~5 TB/s. WIN.
// R4: nontemporal builtins reject HIP_vector_type float4 -> use native
//     ext_vector_type(4). Otherwise same plan: wave-private LDS regions
//     (no __syncthreads; same-wave ds dep ordered by lgkmcnt) + nt
//     loads/stores (268MB write-once should not dirty L2).

typedef float vfloat4 __attribute__((ext_vector_type(4)));

namespace {

struct Tables {
    float knot[20];
    float r1[3][18];   // 1/(knot[p+i]   - knot[i]   + 1e-15), p=1..3
    float r2[3][18];   // 1/(knot[p+1+i] - knot[1+i] + 1e-15)
};

constexpr Tables make_tables() {
    Tables T{};
    const double step = (1.0 + 1e-07) / 13.0;
    for (int i = 0; i < 20; ++i) {
        double v = 0.0;
        if (i < 3)        v = 0.0;
        else if (i <= 15) v = step * (i - 3);     // linspace pts 0..12
        else if (i == 16) v = 1.0 + 1e-07;        // linspace endpoint exact
        else              v = 1.0;
        T.knot[i] = (float)v;
    }
    for (int p = 1; p <= 3; ++p) {
        for (int i = 0; i < 19 - p; ++i) {
            T.r1[p - 1][i] = 1.0f / (T.knot[p + i]     - T.knot[i]     + 1e-15f);
            T.r2[p - 1][i] = 1.0f / (T.knot[p + 1 + i] - T.knot[1 + i] + 1e-15f);
        }
    }
    return T;
}

} // namespace

// Row stride 5 vfloat4 (4 data + 1 pad) = 20 floats: lane l's row starts at
// bank (20*l)%32, uniform spread over all 32 banks in both LDS phases (only
// the inherent b128 aliasing remains). 64 rows x 80B = 5 KB/wave,
// 20 KB/block -> 8 blocks/CU.
#define ROW_STRIDE 5

__global__ __launch_bounds__(256) void bspline_basis_kernel(
    const float* __restrict__ ts, float* __restrict__ out, int n)
{
    constexpr Tables T = make_tables();

    __shared__ vfloat4 lds[4][64 * ROW_STRIDE];

    const int tid  = threadIdx.x;
    const int wave = tid >> 6;
    const int lane = tid & 63;
    const int gid  = blockIdx.x * 256 + tid;

    // ---- Phase 1: one element per thread, full recursion in registers ----
    {
        int e = gid < n ? gid : (n - 1);
        float t = __builtin_nontemporal_load(ts + e);

        float B[19];
#pragma unroll
        for (int i = 0; i < 19; ++i) {
            float kL = T.knot[i], kR = T.knot[i + 1];
            B[i] = (kR > kL && t >= kL && t < kR) ? 1.0f : 0.0f;
        }

#pragma unroll
        for (int p = 1; p <= 3; ++p) {
#pragma unroll
            for (int i = 0; i < 19 - p; ++i) {
                float a = (t - T.knot[i]) * T.r1[p - 1][i];
                float b = (T.knot[p + 1 + i] - t) * T.r2[p - 1][i];
                B[i] = a * B[i] + b * B[i + 1];
            }
        }

        vfloat4* row = &lds[wave][lane * ROW_STRIDE];
        row[0] = (vfloat4){B[0],  B[1],  B[2],  B[3]};
        row[1] = (vfloat4){B[4],  B[5],  B[6],  B[7]};
        row[2] = (vfloat4){B[8],  B[9],  B[10], B[11]};
        row[3] = (vfloat4){B[12], B[13], B[14], B[15]};
    }

    // No __syncthreads: each wave reads back only its own LDS region; the
    // ds_write -> ds_read dependency within a wave is ordered by the
    // compiler-inserted s_waitcnt lgkmcnt.

    // ---- Phase 2: drain this wave's 64 elements in output-linear order ----
    // Wave covers vfloat4 indices [wbase4, wbase4 + 256) of out: each of the
    // 4 store instructions is one contiguous, aligned 1 KB wave span.
    const size_t wbase4 = ((size_t)blockIdx.x * 256 + wave * 64) * 4;
    const size_t limit4 = (size_t)n * 4;
    vfloat4* o = reinterpret_cast<vfloat4*>(out) + wbase4;
#pragma unroll
    for (int m = 0; m < 4; ++m) {
        int idx = lane + 64 * m;          // wave-local vfloat4 index
        int e = idx >> 2;                 // source row in this wave's region
        int l = idx & 3;                  // quarter of the row
        vfloat4 v = lds[wave][e * ROW_STRIDE + l];
        if (wbase4 + (size_t)idx < limit4) {
            __builtin_nontemporal_store(v, o + idx);
        }
    }
}

extern "C" void kernel_launch(void* const* d_in, const int* in_sizes, int n_in,
                              void* d_out, int out_size, void* d_ws, size_t ws_size,
                              hipStream_t stream) {
    const float* ts = (const float*)d_in[0];
    float* out = (float*)d_out;
    int n = in_sizes[0];  // 32 * 131072 = 4194304

    const int block = 256;
    const int grid = (n + block - 1) / block;
    bspline_basis_kernel<<<grid, block, 0, stream>>>(ts, out, n);
}